// Round 13
// baseline (333.831 us; speedup 1.0000x reference)
//
#include <hip/hip_runtime.h>
#include <hip/hip_bf16.h>

#define B_ 4
#define S_ 4096
#define D_ 1024
#define E_ 8
#define F_ 2048
#define TK_ 512

typedef unsigned short u16;
typedef unsigned int u32;
typedef u16 u16x4 __attribute__((ext_vector_type(4)));
typedef u16 u16x8 __attribute__((ext_vector_type(8)));
typedef short s16x8 __attribute__((ext_vector_type(8)));
typedef float f32x4 __attribute__((ext_vector_type(4)));

__device__ __forceinline__ u16 f2bf(float f) {
  u32 u = __builtin_bit_cast(u32, f);
  u32 r = (u + 0x7fffu + ((u >> 16) & 1u)) >> 16;
  return (u16)r;
}
__device__ __forceinline__ float b2f(u16 h) {
  return __builtin_bit_cast(float, ((u32)h) << 16);
}
__device__ __forceinline__ void gload16(const u16* g, const u16* l) {
  __builtin_amdgcn_global_load_lds((const __attribute__((address_space(1))) void*)g,
                                   (__attribute__((address_space(3))) void*)l, 16, 0, 0);
}
__device__ __forceinline__ f32x4 mfma_bf16(s16x8 a, s16x8 b, f32x4 c) {
  return __builtin_amdgcn_mfma_f32_16x16x32_bf16(a, b, c, 0, 0, 0);
}
// tanh-approx GELU (JAX approximate=True form), ~6 VALU ops vs ~20 for erff.
__device__ __forceinline__ float gelu_t(float v) {
  float t = v * (1.5957691216f + 0.0713548162726f * v * v);
  return v / (1.f + __expf(-t));
}

// ---------------- fused: router logits+probs + x->bf16 + zero(G,Bd) ----------------
__global__ __launch_bounds__(256) void rc_kernel(const float* __restrict__ x,
                                                 const float* __restrict__ Wr,
                                                 float* __restrict__ logits,
                                                 float* __restrict__ probs,
                                                 u16* __restrict__ xb,
                                                 float* __restrict__ GBd) {
  __shared__ float wr[D_ * E_];
  for (int i = threadIdx.x; i < D_ * E_; i += 256) wr[i] = Wr[i];
  if (blockIdx.x < 16) {
    float4 z = make_float4(0.f, 0.f, 0.f, 0.f);
    *(float4*)(GBd + (size_t)blockIdx.x * 1024 + threadIdx.x * 4) = z;
  }
  __syncthreads();
  int lane = threadIdx.x & 63;
  int wid = threadIdx.x >> 6;
  int token = blockIdx.x * 4 + wid;
  const float* xr = x + (size_t)token * D_;
  u16* xo = xb + (size_t)token * D_;
  float acc[E_];
#pragma unroll
  for (int e = 0; e < E_; ++e) acc[e] = 0.f;
#pragma unroll
  for (int q = 0; q < 4; ++q) {
    int d0 = q * 256 + lane * 4;
    float4 v = *(const float4*)(xr + d0);
    u16x4 st;
    st[0] = f2bf(v.x); st[1] = f2bf(v.y); st[2] = f2bf(v.z); st[3] = f2bf(v.w);
    *(u16x4*)(xo + d0) = st;
    float xv[4] = {v.x, v.y, v.z, v.w};
    const float* w0 = &wr[d0 * E_];
#pragma unroll
    for (int j = 0; j < 4; ++j) {
#pragma unroll
      for (int e = 0; e < E_; ++e) acc[e] += xv[j] * w0[j * E_ + e];
    }
  }
#pragma unroll
  for (int e = 0; e < E_; ++e) {
#pragma unroll
    for (int off = 32; off; off >>= 1) acc[e] += __shfl_down(acc[e], off);
  }
  if (lane == 0) {
    float4 o0 = make_float4(acc[0], acc[1], acc[2], acc[3]);
    float4 o1 = make_float4(acc[4], acc[5], acc[6], acc[7]);
    *(float4*)(logits + (size_t)token * E_) = o0;
    *(float4*)(logits + (size_t)token * E_ + 4) = o1;
    float mx = acc[0];
#pragma unroll
    for (int t = 1; t < 8; ++t) mx = fmaxf(mx, acc[t]);
    float sum = 0.f;
    float pe[8];
#pragma unroll
    for (int t = 0; t < 8; ++t) { pe[t] = expf(acc[t] - mx); sum += pe[t]; }
    float inv = 1.f / sum;
    float4 p0 = make_float4(pe[0] * inv, pe[1] * inv, pe[2] * inv, pe[3] * inv);
    float4 p1 = make_float4(pe[4] * inv, pe[5] * inv, pe[6] * inv, pe[7] * inv);
    *(float4*)(probs + (size_t)token * E_) = p0;
    *(float4*)(probs + (size_t)token * E_ + 4) = p1;
  }
}

// ---- fused BW-bound pre-pass: topk (0..31) + W1 transpose 4-tile/block +
// ---- zero(results) (32..4127) + W2 transpose 4-tile/block + Bd/G (4128..8223,
// ---- bigws only; small-ws launches without these blocks).
// R11 lesson: per-block work must be ~40KB, not 10KB. Each transpose block
// handles 4 (32x32) tiles in 2 LDS passes (2 tiles of [32][33] f32 = 8.4KB).
__device__ __forceinline__ void suffix_scan(u32* h, int n, int tid) {
  for (int d = 1; d < n; d <<= 1) {
    u32 v[2];
    int c = 0;
    for (int i = tid; i < n; i += 1024) v[c++] = (i + d < n) ? h[i + d] : 0;
    __syncthreads();
    c = 0;
    for (int i = tid; i < n; i += 1024) h[i] += v[c++];
    __syncthreads();
  }
}

__global__ __launch_bounds__(1024) void tk_tr_kernel(const float* __restrict__ probs,
                                                     int* __restrict__ idx,
                                                     float* __restrict__ wts,
                                                     const float* __restrict__ W1,
                                                     u16* __restrict__ W1t,
                                                     float* __restrict__ results,
                                                     const float* __restrict__ W2,
                                                     const float* __restrict__ gamma,
                                                     const float* __restrict__ beta,
                                                     u16* __restrict__ W2g,
                                                     float* __restrict__ Bd,
                                                     float* __restrict__ G) {
  __shared__ u32 keys[S_];   // 16KB; transpose branches reuse as f32 tl[2][32][33]
  __shared__ u32 hist[2048];
  __shared__ u32 tcnt[1024];
  __shared__ u32 sb, sneed, scnt;
  int tid = threadIdx.x;
  if (blockIdx.x >= 32 + 4096) {
    // ---- W2 transpose: 4 (32x32) tiles, 2 passes; gamma-scale + Bd/G sums ----
    int t = blockIdx.x - (32 + 4096);        // 0..4095
    int z = t >> 9, rem = t & 511;           // R=F=2048 (64 r-tiles), cg over D (8 groups of 128)
    int r0 = (rem & 63) * 32, cg = (rem >> 6) * 128;
    float(*tl)[32][33] = (float(*)[32][33])keys;
    const float* s = W2 + (size_t)z * F_ * D_;
    u16* dd = W2g + (size_t)z * D_ * F_;
    int xx = tid & 31, yy = (tid >> 5) & 31, qq = tid >> 10;  // qq==0 (1024 thr)
    (void)qq;
    float gsc = gamma[(size_t)z * F_ + r0 + xx];  // scale by source-row gamma (row = r0+xx after transpose)
#pragma unroll
    for (int p = 0; p < 2; ++p) {
      int q0 = tid >> 9;                     // 0..1: tile within pass
      int lt = tid & 511;                    // 512 threads per tile
      int ly = lt >> 4, lx2 = (lt & 15) * 2; // 32 rows x 16 col-pairs
      int c0 = cg + (p * 2 + q0) * 32;
      tl[q0][ly][lx2] = s[(size_t)(r0 + ly) * D_ + c0 + lx2];
      tl[q0][ly][lx2 + 1] = s[(size_t)(r0 + ly) * D_ + c0 + lx2 + 1];
      __syncthreads();
      // transposed write: out[c0+yy][r0+xx], tile q for this thread's halves
#pragma unroll
      for (int q = 0; q < 2; ++q) {
        int c0q = cg + (p * 2 + q) * 32;
        dd[(size_t)(c0q + yy) * F_ + r0 + xx] = f2bf(gsc * tl[q][xx][yy]);
      }
      // col-sums: threads 0..63 -> (tile q, col cc)
      if (tid < 64) {
        int q = tid >> 5, cc = tid & 31;
        int c0q = cg + (p * 2 + q) * 32;
        float smb = 0.f, smg = 0.f;
        const float* br = beta + (size_t)z * F_ + r0;
        const float* gr = gamma + (size_t)z * F_ + r0;
#pragma unroll
        for (int f = 0; f < 32; ++f) {
          smb += br[f] * tl[q][f][cc];
          smg += gr[f] * tl[q][f][cc];
        }
        unsafeAtomicAdd(&Bd[(size_t)z * D_ + c0q + cc], smb);
        unsafeAtomicAdd(&G[(size_t)z * D_ + c0q + cc], smg);
      }
      __syncthreads();
    }
    return;
  }
  if (blockIdx.x >= 32) {
    // ---- W1 transpose: 4 (32x32) tiles, 2 passes + zero-results 16KB ----
    int t = blockIdx.x - 32;                 // 0..4095
    int z = t >> 9, rem = t & 511;           // R=D=1024 (32 r-tiles), cg over F (16 groups of 128)
    int r0 = (rem & 31) * 32, cg = (rem >> 5) * 128;
    float(*tl)[32][33] = (float(*)[32][33])keys;
    const float* s = W1 + (size_t)z * D_ * F_;
    u16* d = W1t + (size_t)z * D_ * F_;
    int xx = tid & 31, yy = (tid >> 5) & 31;
    float4 zf = make_float4(0.f, 0.f, 0.f, 0.f);
    *(float4*)(results + (size_t)t * 4096 + tid * 4) = zf;  // 4096 blocks x 16KB = 64MB
#pragma unroll
    for (int p = 0; p < 2; ++p) {
      int q0 = tid >> 9;
      int lt = tid & 511;
      int ly = lt >> 4, lx2 = (lt & 15) * 2;
      int c0 = cg + (p * 2 + q0) * 32;
      tl[q0][ly][lx2] = s[(size_t)(r0 + ly) * F_ + c0 + lx2];
      tl[q0][ly][lx2 + 1] = s[(size_t)(r0 + ly) * F_ + c0 + lx2 + 1];
      __syncthreads();
#pragma unroll
      for (int q = 0; q < 2; ++q) {
        int c0q = cg + (p * 2 + q) * 32;
        d[(size_t)(c0q + yy) * D_ + r0 + xx] = f2bf(tl[q][xx][yy]);
      }
      __syncthreads();
    }
    return;
  }
  // ---- top-k per (b,e): exact 3-level radix-histogram select ----
  int be = blockIdx.x, b = be >> 3, e = be & 7;
  const float* pr = probs + (size_t)b * S_ * E_ + e;
  for (int s = tid; s < S_; s += 1024) keys[s] = __builtin_bit_cast(u32, pr[(size_t)s * E_]);
  if (tid == 0) scnt = 0;

  hist[tid] = 0; hist[tid + 1024] = 0;
  __syncthreads();
  for (int s = tid; s < S_; s += 1024) atomicAdd(&hist[keys[s] >> 21], 1u);
  __syncthreads();
  suffix_scan(hist, 2048, tid);
  for (int i = tid; i < 2048; i += 1024) {
    u32 nxt = (i + 1 < 2048) ? hist[i + 1] : 0;
    if (hist[i] >= (u32)TK_ && nxt < (u32)TK_) { sb = (u32)i; sneed = TK_ - nxt; }
  }
  __syncthreads();
  u32 b1 = sb, need1 = sneed;
  __syncthreads();

  hist[tid] = 0; hist[tid + 1024] = 0;
  __syncthreads();
  for (int s = tid; s < S_; s += 1024)
    if ((keys[s] >> 21) == b1) atomicAdd(&hist[(keys[s] >> 10) & 2047u], 1u);
  __syncthreads();
  suffix_scan(hist, 2048, tid);
  for (int i = tid; i < 2048; i += 1024) {
    u32 nxt = (i + 1 < 2048) ? hist[i + 1] : 0;
    if (hist[i] >= need1 && nxt < need1) { sb = (u32)i; sneed = need1 - nxt; }
  }
  __syncthreads();
  u32 p2 = (b1 << 11) | sb, need2 = sneed;
  __syncthreads();

  if (tid < 1024) hist[tid] = 0;
  __syncthreads();
  for (int s = tid; s < S_; s += 1024)
    if ((keys[s] >> 10) == p2) atomicAdd(&hist[keys[s] & 1023u], 1u);
  __syncthreads();
  suffix_scan(hist, 1024, tid);
  for (int i = tid; i < 1024; i += 1024) {
    u32 nxt = (i + 1 < 1024) ? hist[i + 1] : 0;
    if (hist[i] >= need2 && nxt < need2) { sb = (u32)i; sneed = need2 - nxt; }
  }
  __syncthreads();
  u32 T = (p2 << 10) | sb;
  u32 needT = sneed;

  for (int s = tid; s < S_; s += 1024) {
    if (keys[s] > T) {
      u32 p = atomicAdd(&scnt, 1u);
      idx[be * TK_ + p] = s;
      wts[be * TK_ + p] = __builtin_bit_cast(float, keys[s]);
    }
  }
  u32 myc = 0;
#pragma unroll
  for (int j = 0; j < 4; ++j) myc += (keys[tid * 4 + j] == T) ? 1u : 0u;
  tcnt[tid] = myc;
  __syncthreads();
  for (int d = 1; d < 1024; d <<= 1) {
    u32 v = (tid >= d) ? tcnt[tid - d] : 0;
    __syncthreads();
    tcnt[tid] += v;
    __syncthreads();
  }
  u32 rank = tcnt[tid] - myc;
#pragma unroll
  for (int j = 0; j < 4; ++j) {
    int s = tid * 4 + j;
    if (keys[s] == T) {
      if (rank < needT) {
        u32 p = atomicAdd(&scnt, 1u);
        idx[be * TK_ + p] = s;
        wts[be * TK_ + p] = __builtin_bit_cast(float, T);
      }
      rank++;
    }
  }
}

// ---------------- W2 transpose (standalone 256-thr, small-ws fallback only) ----------------
__global__ __launch_bounds__(256) void transpose_cvt_kernel(const float* __restrict__ src,
                                                            u16* __restrict__ dst,
                                                            int R, int C,
                                                            const float* __restrict__ scale,
                                                            const float* __restrict__ beta,
                                                            float* __restrict__ Bd,
                                                            float* __restrict__ G) {
  __shared__ float tile[32][33];
  int z = blockIdx.z;
  const float* s = src + (size_t)z * R * C;
  u16* d = dst + (size_t)z * R * C;
  int r0 = blockIdx.x * 32, c0 = blockIdx.y * 32;
  int xx = threadIdx.x & 31, yy = threadIdx.x >> 5;
#pragma unroll
  for (int q = 0; q < 4; ++q)
    tile[yy + q * 8][xx] = s[(size_t)(r0 + yy + q * 8) * C + c0 + xx];
  __syncthreads();
  float sc = scale[(size_t)z * R + r0 + xx];
#pragma unroll
  for (int q = 0; q < 4; ++q)
    d[(size_t)(c0 + yy + q * 8) * R + r0 + xx] = f2bf(sc * tile[xx][yy + q * 8]);
  __syncthreads();
  if (threadIdx.x < 32) {
    float smb = 0.f, smg = 0.f;
    const float* br = beta + (size_t)z * R + r0;
    const float* gr = scale + (size_t)z * R + r0;
#pragma unroll
    for (int f = 0; f < 32; ++f) {
      smb += br[f] * tile[f][threadIdx.x];
      smg += gr[f] * tile[f][threadIdx.x];
    }
    unsafeAtomicAdd(&Bd[(size_t)z * C + c0 + threadIdx.x], smb);
    unsafeAtomicAdd(&G[(size_t)z * C + c0 + threadIdx.x], smg);
  }
}

// =====================================================================
// m97-structure K-loop (verified R4/R5/R7): 128x128 tile, BK=64, 4 waves,
// single-buffer 32KB LDS, cross-block TLP hides the vmcnt(0) drain.
// G4 swizzle slot^=(row&7), both sides. DO NOT restructure (R3/R6 lesson).
// =====================================================================
__device__ __forceinline__ void kloop97(const u16* const pa[4], const u16* const pb[4],
                                        u16* As, u16* Bs, f32x4 acc[4][4], int NT,
                                        int wid, const int aoff[4], const int boff[4],
                                        int sk0, int sk1) {
  int ldst = wid * 512;
  for (int t = 0; t < NT; ++t) {
    int k0 = t * 64;
#pragma unroll
    for (int q = 0; q < 4; ++q) gload16(pa[q] + k0, As + q * 2048 + ldst);
#pragma unroll
    for (int q = 0; q < 4; ++q) gload16(pb[q] + k0, Bs + q * 2048 + ldst);
    asm volatile("s_waitcnt vmcnt(0)" ::: "memory");
    __builtin_amdgcn_s_barrier();
    s16x8 aF[4], bF[4];
#pragma unroll
    for (int kk = 0; kk < 2; ++kk) {
      int sk = kk ? sk1 : sk0;
#pragma unroll
      for (int f = 0; f < 4; ++f) aF[f] = *(const s16x8*)&As[aoff[f] + sk];
#pragma unroll
      for (int g = 0; g < 4; ++g) bF[g] = *(const s16x8*)&Bs[boff[g] + sk];
      __builtin_amdgcn_s_setprio(1);
#pragma unroll
      for (int f = 0; f < 4; ++f)
#pragma unroll
        for (int g = 0; g < 4; ++g) acc[f][g] = mfma_bf16(aF[f], bF[g], acc[f][g]);
      __builtin_amdgcn_s_setprio(0);
    }
    __builtin_amdgcn_s_barrier();
  }
}

// ---------------- GEMM1: h = gelu(gather(xb) @ W1t^T + b1) + per-row LN stats ----------------
__global__ __launch_bounds__(256, 2) void gemm1_kernel(const u16* __restrict__ xb,
                                                       const u16* __restrict__ W1t,
                                                       const float* __restrict__ b1,
                                                       const int* __restrict__ idx,
                                                       u16* __restrict__ hbuf,
                                                       float2* __restrict__ stats2) {
  int p = blockIdx.x;
  int e = p & 7, slot = p >> 3;
  int tm = slot & 3, bb = (slot >> 2) & 3, tn = slot >> 4;
  int be = bb * 8 + e;
  int t0 = tm * 128, n0 = tn * 128;
  int tid = threadIdx.x, lane = tid & 63, wid = tid >> 6;
  int wm = wid >> 1, wn = wid & 1;
  int cidx = lane & 15, kq = lane >> 4;
  __shared__ u16 As[128 * 64];
  __shared__ u16 Bs[128 * 64];
  __shared__ float2 sm[128][2];

  int srow = tid >> 3;
  int kc = (tid & 7) ^ (srow & 7);
  const u16* pa[4];
  const u16* pb[4];
  const u16* bsrc = W1t + (size_t)e * F_ * D_;
#pragma unroll
  for (int q = 0; q < 4; ++q) {
    int tok = idx[be * TK_ + t0 + q * 32 + srow];
    pa[q] = xb + ((size_t)bb * S_ + tok) * D_ + kc * 8;
    pb[q] = bsrc + (size_t)(n0 + q * 32 + srow) * D_ + kc * 8;
  }
  int aoff[4], boff[4];
#pragma unroll
  for (int f = 0; f < 4; ++f) {
    aoff[f] = (wm * 64 + f * 16 + cidx) * 64;
    boff[f] = (wn * 64 + f * 16 + cidx) * 64;
  }
  int sk0 = (kq ^ (cidx & 7)) * 8;
  int sk1 = ((4 + kq) ^ (cidx & 7)) * 8;

  f32x4 acc[4][4];
#pragma unroll
  for (int f = 0; f < 4; ++f)
#pragma unroll
    for (int g = 0; g < 4; ++g) acc[f][g] = (f32x4){0.f, 0.f, 0.f, 0.f};

  kloop97(pa, pb, As, Bs, acc, D_ / 64, wid, aoff, boff, sk0, sk1);

  float bias[4];
#pragma unroll
  for (int g = 0; g < 4; ++g) bias[g] = b1[e * F_ + n0 + wn * 64 + g * 16 + cidx];
  size_t hbase = (size_t)be * TK_ * F_;
#pragma unroll
  for (int f = 0; f < 4; ++f) {
#pragma unroll
    for (int r = 0; r < 4; ++r) {
      int lr = wm * 64 + f * 16 + kq * 4 + r;
      size_t hb = hbase + (size_t)(t0 + lr) * F_ + n0 + wn * 64 + cidx;
      float vs = 0.f, vss = 0.f;
#pragma unroll
      for (int g = 0; g < 4; ++g) {
        float v = acc[f][g][r] + bias[g];
        float gl = gelu_t(v);
        hbuf[hb + g * 16] = f2bf(gl);
        vs += gl;
        vss += gl * gl;
      }
#pragma unroll
      for (int off = 1; off < 16; off <<= 1) {
        vs += __shfl_xor(vs, off);
        vss += __shfl_xor(vss, off);
      }
      if (cidx == 0) {
        float2 o; o.x = vs; o.y = vss;
        sm[lr][wn] = o;
      }
    }
  }
  __syncthreads();
  if (tid < 128) {
    float2 a = sm[tid][0], b = sm[tid][1];
    float2 o; o.x = a.x + b.x; o.y = a.y + b.y;
    stats2[((size_t)be * TK_ + t0 + tid) * 16 + tn] = o;
  }
}

// ---------------- GEMM2 (R7 form): out = rstd*(h @ W2g) - rstd*mean*G + Bd + b2 ----------------
__global__ __launch_bounds__(256, 2) void gemm2_kernel(const u16* __restrict__ hbuf,
                                                       const u16* __restrict__ W2g,
                                                       const float* __restrict__ b2,
                                                       const int* __restrict__ idx,
                                                       const float* __restrict__ wts,
                                                       float* __restrict__ results,
                                                       const float2* __restrict__ stats2,
                                                       const float* __restrict__ G,
                                                       const float* __restrict__ Bd) {
  int p = blockIdx.x;
  int e = p & 7, slot = p >> 3;
  int tn = slot & 7, tm = (slot >> 3) & 3, bb = slot >> 5;
  int be = bb * 8 + e;
  int t0 = tm * 128, n0 = tn * 128;
  int tid = threadIdx.x, lane = tid & 63, wid = tid >> 6;
  int wm = wid >> 1, wn = wid & 1;
  int cidx = lane & 15, kq = lane >> 4;
  __shared__ u16 As[128 * 64];
  __shared__ u16 Bs[128 * 64];
  __shared__ float smean[128];
  __shared__ float srstd[128];

  if (tid < 128) {
    const float2* sp = stats2 + ((size_t)be * TK_ + t0 + tid) * 16;
    float sum = 0.f, ss = 0.f;
#pragma unroll
    for (int j = 0; j < 16; ++j) {
      float2 v = sp[j];
      sum += v.x;
      ss += v.y;
    }
    float mean = sum * (1.f / F_);
    float var = ss * (1.f / F_) - mean * mean;
    smean[tid] = mean;
    srstd[tid] = rsqrtf(var + 1e-5f);
  }
  __syncthreads();

  int srow = tid >> 3;
  int kc = (tid & 7) ^ (srow & 7);
  const u16* pa[4];
  const u16* pb[4];
  const u16* asrc = hbuf + (size_t)be * TK_ * F_;
  const u16* bsrc = W2g + (size_t)e * D_ * F_;
#pragma unroll
  for (int q = 0; q < 4; ++q) {
    pa[q] = asrc + (size_t)(t0 + q * 32 + srow) * F_ + kc * 8;
    pb[q] = bsrc + (size_t)(n0 + q * 32 + srow) * F_ + kc * 8;
  }
  int aoff[4], boff[4];
#pragma unroll
  for (int f = 0; f < 4; ++f) {
    aoff[f] = (wm * 64 + f * 16 + cidx) * 64;
    boff[f] = (wn * 64 + f * 16 + cidx) * 64;
  }
  int sk0 = (kq ^ (cidx & 7)) * 8;
  int sk1 = ((4 + kq) ^ (cidx & 7)) * 8;

  f32x4 acc[4][4];
#pragma unroll
  for (int f = 0; f < 4; ++f)
#pragma unroll
    for (int g = 0; g < 4; ++g) acc[f][g] = (f32x4){0.f, 0.f, 0.f, 0.f};

  kloop97(pa, pb, As, Bs, acc, F_ / 64, wid, aoff, boff, sk0, sk1);

  int cb = n0 + wn * 64 + cidx;
  float b2v[4], Gv[4], Bdv[4];
#pragma unroll
  for (int g = 0; g < 4; ++g) {
    b2v[g] = b2[e * D_ + cb + g * 16];
    Gv[g] = G[e * D_ + cb + g * 16];
    Bdv[g] = Bd[e * D_ + cb + g * 16];
  }
#pragma unroll
  for (int f = 0; f < 4; ++f) {
#pragma unroll
    for (int r = 0; r < 4; ++r) {
      int lr = wm * 64 + f * 16 + kq * 4 + r;
      int trow = t0 + lr;
      int tok = idx[be * TK_ + trow];
      float wv = wts[be * TK_ + trow];
      float mean = smean[lr], rstd = srstd[lr];
      float* rrow = results + ((size_t)bb * S_ + tok) * D_ + cb;
#pragma unroll
      for (int g = 0; g < 4; ++g) {
        float out = rstd * acc[f][g][r] - rstd * mean * Gv[g] + Bdv[g] + b2v[g];
        unsafeAtomicAdd(rrow + g * 16, wv * out);
      }
    }
  }
}

extern "C" void kernel_launch(void* const* d_in, const int* in_sizes, int n_in,
                              void* d_out, int out_size, void* d_ws, size_t ws_size,
                              hipStream_t stream) {
  const float* x = (const float*)d_in[0];
  const float* Wr = (const float*)d_in[1];
  const float* W1 = (const float*)d_in[2];
  const float* b1 = (const float*)d_in[3];
  const float* gamma = (const float*)d_in[4];
  const float* beta = (const float*)d_in[5];
  const float* W2 = (const float*)d_in[6];
  const float* b2 = (const float*)d_in[7];

  float* results = (float*)d_out;
  float* logits = results + (size_t)B_ * S_ * D_;

  char* ws = (char*)d_ws;
  const size_t OFF_IDX = 0;                                       // 64 KB
  const size_t OFF_WTS = OFF_IDX + (size_t)B_ * E_ * TK_ * 4;     // 64 KB
  const size_t OFF_ST = OFF_WTS + (size_t)B_ * E_ * TK_ * 4;      // 2 MB stats2
  const size_t OFF_G = OFF_ST + (size_t)B_ * E_ * TK_ * 16 * 8;   // 32 KB
  const size_t OFF_BD = OFF_G + (size_t)E_ * D_ * 4;              // 32 KB (contig w/ G)
  const size_t OFF_P = OFF_BD + (size_t)E_ * D_ * 4;              // 512 KB probs
  const size_t OFF_R0 = OFF_P + (size_t)B_ * S_ * E_ * 4;         // 32 MB: xb (W2g alias in small-ws)
  const size_t OFF_R1 = OFF_R0 + (size_t)E_ * D_ * F_ * 2;        // 32 MB: W1t
  const size_t OFF_H = OFF_R1 + (size_t)E_ * D_ * F_ * 2;         // 64 MB: hbuf
  const size_t NEED = OFF_H + (size_t)B_ * E_ * TK_ * F_ * 2;
  const size_t OFF_W2G = NEED;                                    // +32 MB (big-ws only)
  const size_t NEED_BIG = OFF_W2G + (size_t)E_ * D_ * F_ * 2;
  if (ws_size < NEED) return;
  bool bigws = ws_size >= NEED_BIG;

  int* idx = (int*)(ws + OFF_IDX);
  float* wts = (float*)(ws + OFF_WTS);
  float2* stats2 = (float2*)(ws + OFF_ST);
  float* G = (float*)(ws + OFF_G);
  float* Bd = (float*)(ws + OFF_BD);
  float* probs = (float*)(ws + OFF_P);
  u16* xb = (u16*)(ws + OFF_R0);
  u16* W1t = (u16*)(ws + OFF_R1);
  u16* hbuf = (u16*)(ws + OFF_H);
  u16* W2g = bigws ? (u16*)(ws + OFF_W2G) : (u16*)(ws + OFF_R0);

  rc_kernel<<<dim3(B_ * S_ / 4), 256, 0, stream>>>(x, Wr, logits, probs, xb, G);
  // BW-bound pre-pass: topk + W1t + zero(results) [+ W2g/Bd/G if bigws]
  int trgrid = bigws ? (32 + 4096 + 4096) : (32 + 4096);
  tk_tr_kernel<<<dim3(trgrid), 1024, 0, stream>>>(probs, idx, wts, W1, W1t, results,
                                                  W2, gamma, beta, W2g, Bd, G);
  gemm1_kernel<<<dim3(2048), 256, 0, stream>>>(xb, W1t, b1, idx, hbuf, stats2);
  if (!bigws) {
    // W2g overwrites xb region only after gemm1 completed (in-order stream)
    transpose_cvt_kernel<<<dim3(F_ / 32, D_ / 32, E_), 256, 0, stream>>>(
        W2, W2g, F_, D_, gamma, beta, Bd, G);
  }
  gemm2_kernel<<<dim3(1024), 256, 0, stream>>>(hbuf, W2g, b2, idx, wts, results,
                                               stats2, G, Bd);
}

// Round 14
// 310.533 us; speedup vs baseline: 1.0750x; 1.0750x over previous
//
#include <hip/hip_runtime.h>
#include <hip/hip_bf16.h>

#define B_ 4
#define S_ 4096
#define D_ 1024
#define E_ 8
#define F_ 2048
#define TK_ 512

typedef unsigned short u16;
typedef unsigned int u32;
typedef u16 u16x4 __attribute__((ext_vector_type(4)));
typedef u16 u16x8 __attribute__((ext_vector_type(8)));
typedef short s16x8 __attribute__((ext_vector_type(8)));
typedef float f32x4 __attribute__((ext_vector_type(4)));

__device__ __forceinline__ u16 f2bf(float f) {
  u32 u = __builtin_bit_cast(u32, f);
  u32 r = (u + 0x7fffu + ((u >> 16) & 1u)) >> 16;
  return (u16)r;
}
__device__ __forceinline__ float b2f(u16 h) {
  return __builtin_bit_cast(float, ((u32)h) << 16);
}
__device__ __forceinline__ void gload16(const u16* g, const u16* l) {
  __builtin_amdgcn_global_load_lds((const __attribute__((address_space(1))) void*)g,
                                   (__attribute__((address_space(3))) void*)l, 16, 0, 0);
}
__device__ __forceinline__ f32x4 mfma_bf16(s16x8 a, s16x8 b, f32x4 c) {
  return __builtin_amdgcn_mfma_f32_16x16x32_bf16(a, b, c, 0, 0, 0);
}
// tanh-approx GELU (JAX approximate=True form), ~6 VALU ops vs ~20 for erff.
__device__ __forceinline__ float gelu_t(float v) {
  float t = v * (1.5957691216f + 0.0713548162726f * v * v);
  return v / (1.f + __expf(-t));
}

// ---------------- fused: router logits+probs + x->bf16 + zero(G,Bd) ----------------
__global__ __launch_bounds__(256) void rc_kernel(const float* __restrict__ x,
                                                 const float* __restrict__ Wr,
                                                 float* __restrict__ logits,
                                                 float* __restrict__ probs,
                                                 u16* __restrict__ xb,
                                                 float* __restrict__ GBd) {
  __shared__ float wr[D_ * E_];
  for (int i = threadIdx.x; i < D_ * E_; i += 256) wr[i] = Wr[i];
  if (blockIdx.x < 16) {
    float4 z = make_float4(0.f, 0.f, 0.f, 0.f);
    *(float4*)(GBd + (size_t)blockIdx.x * 1024 + threadIdx.x * 4) = z;
  }
  __syncthreads();
  int lane = threadIdx.x & 63;
  int wid = threadIdx.x >> 6;
  int token = blockIdx.x * 4 + wid;
  const float* xr = x + (size_t)token * D_;
  u16* xo = xb + (size_t)token * D_;
  float acc[E_];
#pragma unroll
  for (int e = 0; e < E_; ++e) acc[e] = 0.f;
#pragma unroll
  for (int q = 0; q < 4; ++q) {
    int d0 = q * 256 + lane * 4;
    float4 v = *(const float4*)(xr + d0);
    u16x4 st;
    st[0] = f2bf(v.x); st[1] = f2bf(v.y); st[2] = f2bf(v.z); st[3] = f2bf(v.w);
    *(u16x4*)(xo + d0) = st;
    float xv[4] = {v.x, v.y, v.z, v.w};
    const float* w0 = &wr[d0 * E_];
#pragma unroll
    for (int j = 0; j < 4; ++j) {
#pragma unroll
      for (int e = 0; e < E_; ++e) acc[e] += xv[j] * w0[j * E_ + e];
    }
  }
#pragma unroll
  for (int e = 0; e < E_; ++e) {
#pragma unroll
    for (int off = 32; off; off >>= 1) acc[e] += __shfl_down(acc[e], off);
  }
  if (lane == 0) {
    float4 o0 = make_float4(acc[0], acc[1], acc[2], acc[3]);
    float4 o1 = make_float4(acc[4], acc[5], acc[6], acc[7]);
    *(float4*)(logits + (size_t)token * E_) = o0;
    *(float4*)(logits + (size_t)token * E_ + 4) = o1;
    float mx = acc[0];
#pragma unroll
    for (int t = 1; t < 8; ++t) mx = fmaxf(mx, acc[t]);
    float sum = 0.f;
    float pe[8];
#pragma unroll
    for (int t = 0; t < 8; ++t) { pe[t] = expf(acc[t] - mx); sum += pe[t]; }
    float inv = 1.f / sum;
    float4 p0 = make_float4(pe[0] * inv, pe[1] * inv, pe[2] * inv, pe[3] * inv);
    float4 p1 = make_float4(pe[4] * inv, pe[5] * inv, pe[6] * inv, pe[7] * inv);
    *(float4*)(probs + (size_t)token * E_) = p0;
    *(float4*)(probs + (size_t)token * E_ + 4) = p1;
  }
}

// ---------------- fused: topk (blocks 0..31) + W1 transpose + zero(results) ----------------
__device__ __forceinline__ void suffix_scan(u32* h, int n, int tid) {
  for (int d = 1; d < n; d <<= 1) {
    u32 v[2];
    int c = 0;
    for (int i = tid; i < n; i += 1024) v[c++] = (i + d < n) ? h[i + d] : 0;
    __syncthreads();
    c = 0;
    for (int i = tid; i < n; i += 1024) h[i] += v[c++];
    __syncthreads();
  }
}

__global__ __launch_bounds__(1024) void tk_tr_kernel(const float* __restrict__ probs,
                                                     int* __restrict__ idx,
                                                     float* __restrict__ wts,
                                                     const float* __restrict__ W1,
                                                     u16* __restrict__ W1t,
                                                     float* __restrict__ results) {
  __shared__ u32 keys[S_];   // 16KB; transpose branch reuses as f32 tile[32][33]
  __shared__ u32 hist[2048];
  __shared__ u32 tcnt[1024];
  __shared__ u32 sb, sneed, scnt;
  int tid = threadIdx.x;
  if (blockIdx.x >= 32) {
    // ---- W1 transpose tile + zero-results chunk ----
    int t = blockIdx.x - 32;                 // 0..16383
    int z = t >> 11, rem = t & 2047;         // 2048 tiles/expert
    int r0 = (rem & 31) * 32, c0 = (rem >> 5) * 32;  // R=D=1024 (32), C=F=2048 (64)
    float(*tile)[33] = (float(*)[33])keys;
    const float* s = W1 + (size_t)z * D_ * F_;
    u16* d = W1t + (size_t)z * D_ * F_;
    int xx = tid & 31, yy = tid >> 5;
    tile[yy][xx] = s[(size_t)(r0 + yy) * F_ + c0 + xx];
    results[(size_t)t * 1024 + tid] = 0.f;   // 16384*1024 = B*S*D exactly
    __syncthreads();
    d[(size_t)(c0 + yy) * D_ + r0 + xx] = f2bf(tile[xx][yy]);
    return;
  }
  // ---- top-k per (b,e): exact 3-level radix-histogram select ----
  int be = blockIdx.x, b = be >> 3, e = be & 7;
  const float* pr = probs + (size_t)b * S_ * E_ + e;
  for (int s = tid; s < S_; s += 1024) keys[s] = __builtin_bit_cast(u32, pr[(size_t)s * E_]);
  if (tid == 0) scnt = 0;

  hist[tid] = 0; hist[tid + 1024] = 0;
  __syncthreads();
  for (int s = tid; s < S_; s += 1024) atomicAdd(&hist[keys[s] >> 21], 1u);
  __syncthreads();
  suffix_scan(hist, 2048, tid);
  for (int i = tid; i < 2048; i += 1024) {
    u32 nxt = (i + 1 < 2048) ? hist[i + 1] : 0;
    if (hist[i] >= (u32)TK_ && nxt < (u32)TK_) { sb = (u32)i; sneed = TK_ - nxt; }
  }
  __syncthreads();
  u32 b1 = sb, need1 = sneed;
  __syncthreads();

  hist[tid] = 0; hist[tid + 1024] = 0;
  __syncthreads();
  for (int s = tid; s < S_; s += 1024)
    if ((keys[s] >> 21) == b1) atomicAdd(&hist[(keys[s] >> 10) & 2047u], 1u);
  __syncthreads();
  suffix_scan(hist, 2048, tid);
  for (int i = tid; i < 2048; i += 1024) {
    u32 nxt = (i + 1 < 2048) ? hist[i + 1] : 0;
    if (hist[i] >= need1 && nxt < need1) { sb = (u32)i; sneed = need1 - nxt; }
  }
  __syncthreads();
  u32 p2 = (b1 << 11) | sb, need2 = sneed;
  __syncthreads();

  if (tid < 1024) hist[tid] = 0;
  __syncthreads();
  for (int s = tid; s < S_; s += 1024)
    if ((keys[s] >> 10) == p2) atomicAdd(&hist[keys[s] & 1023u], 1u);
  __syncthreads();
  suffix_scan(hist, 1024, tid);
  for (int i = tid; i < 1024; i += 1024) {
    u32 nxt = (i + 1 < 1024) ? hist[i + 1] : 0;
    if (hist[i] >= need2 && nxt < need2) { sb = (u32)i; sneed = need2 - nxt; }
  }
  __syncthreads();
  u32 T = (p2 << 10) | sb;
  u32 needT = sneed;

  for (int s = tid; s < S_; s += 1024) {
    if (keys[s] > T) {
      u32 p = atomicAdd(&scnt, 1u);
      idx[be * TK_ + p] = s;
      wts[be * TK_ + p] = __builtin_bit_cast(float, keys[s]);
    }
  }
  u32 myc = 0;
#pragma unroll
  for (int j = 0; j < 4; ++j) myc += (keys[tid * 4 + j] == T) ? 1u : 0u;
  tcnt[tid] = myc;
  __syncthreads();
  for (int d = 1; d < 1024; d <<= 1) {
    u32 v = (tid >= d) ? tcnt[tid - d] : 0;
    __syncthreads();
    tcnt[tid] += v;
    __syncthreads();
  }
  u32 rank = tcnt[tid] - myc;
#pragma unroll
  for (int j = 0; j < 4; ++j) {
    int s = tid * 4 + j;
    if (keys[s] == T) {
      if (rank < needT) {
        u32 p = atomicAdd(&scnt, 1u);
        idx[be * TK_ + p] = s;
        wts[be * TK_ + p] = __builtin_bit_cast(float, T);
      }
      rank++;
    }
  }
}

// ---------------- standalone W2 transpose (small-ws fallback path) ----------------
__global__ __launch_bounds__(256) void transpose_cvt_kernel(const float* __restrict__ src,
                                                            u16* __restrict__ dst,
                                                            int R, int C,
                                                            const float* __restrict__ scale,
                                                            const float* __restrict__ beta,
                                                            float* __restrict__ Bd,
                                                            float* __restrict__ G) {
  __shared__ float tile[32][33];
  int z = blockIdx.z;
  const float* s = src + (size_t)z * R * C;
  u16* d = dst + (size_t)z * R * C;
  int r0 = blockIdx.x * 32, c0 = blockIdx.y * 32;
  int xx = threadIdx.x & 31, yy = threadIdx.x >> 5;
#pragma unroll
  for (int q = 0; q < 4; ++q)
    tile[yy + q * 8][xx] = s[(size_t)(r0 + yy + q * 8) * C + c0 + xx];
  __syncthreads();
  float sc = scale[(size_t)z * R + r0 + xx];
#pragma unroll
  for (int q = 0; q < 4; ++q)
    d[(size_t)(c0 + yy + q * 8) * R + r0 + xx] = f2bf(sc * tile[xx][yy + q * 8]);
  __syncthreads();
  if (threadIdx.x < 32) {
    float smb = 0.f, smg = 0.f;
    const float* br = beta + (size_t)z * R + r0;
    const float* gr = scale + (size_t)z * R + r0;
#pragma unroll
    for (int f = 0; f < 32; ++f) {
      smb += br[f] * tile[f][threadIdx.x];
      smg += gr[f] * tile[f][threadIdx.x];
    }
    unsafeAtomicAdd(&Bd[(size_t)z * C + c0 + threadIdx.x], smb);
    unsafeAtomicAdd(&G[(size_t)z * C + c0 + threadIdx.x], smg);
  }
}

// =====================================================================
// m97-structure K-loop (verified R4/R5/R7): 128x128 tile, BK=64, 4 waves,
// single-buffer 32KB LDS, cross-block TLP hides the vmcnt(0) drain.
// G4 swizzle slot^=(row&7), both sides. DO NOT restructure (R3/R6 lesson).
// =====================================================================
__device__ __forceinline__ void kloop97(const u16* const pa[4], const u16* const pb[4],
                                        u16* As, u16* Bs, f32x4 acc[4][4], int NT,
                                        int wid, const int aoff[4], const int boff[4],
                                        int sk0, int sk1) {
  int ldst = wid * 512;
  for (int t = 0; t < NT; ++t) {
    int k0 = t * 64;
#pragma unroll
    for (int q = 0; q < 4; ++q) gload16(pa[q] + k0, As + q * 2048 + ldst);
#pragma unroll
    for (int q = 0; q < 4; ++q) gload16(pb[q] + k0, Bs + q * 2048 + ldst);
    asm volatile("s_waitcnt vmcnt(0)" ::: "memory");
    __builtin_amdgcn_s_barrier();
    s16x8 aF[4], bF[4];
#pragma unroll
    for (int kk = 0; kk < 2; ++kk) {
      int sk = kk ? sk1 : sk0;
#pragma unroll
      for (int f = 0; f < 4; ++f) aF[f] = *(const s16x8*)&As[aoff[f] + sk];
#pragma unroll
      for (int g = 0; g < 4; ++g) bF[g] = *(const s16x8*)&Bs[boff[g] + sk];
      __builtin_amdgcn_s_setprio(1);
#pragma unroll
      for (int f = 0; f < 4; ++f)
#pragma unroll
        for (int g = 0; g < 4; ++g) acc[f][g] = mfma_bf16(aF[f], bF[g], acc[f][g]);
      __builtin_amdgcn_s_setprio(0);
    }
    __builtin_amdgcn_s_barrier();
  }
}

// ---------------- GEMM1 (blocks <2048) + W2-transpose tail blocks (>=2048, bigws) ----------------
__global__ __launch_bounds__(256, 2) void gemm1_kernel(const u16* __restrict__ xb,
                                                       const u16* __restrict__ W1t,
                                                       const float* __restrict__ b1,
                                                       const int* __restrict__ idx,
                                                       u16* __restrict__ hbuf,
                                                       float2* __restrict__ stats2,
                                                       const float* __restrict__ W2,
                                                       const float* __restrict__ gamma,
                                                       const float* __restrict__ beta,
                                                       u16* __restrict__ W2g,
                                                       float* __restrict__ Bd,
                                                       float* __restrict__ G) {
  __shared__ u16 As[128 * 64];
  __shared__ u16 Bs[128 * 64];
  __shared__ float2 sm[128][2];
  int tid = threadIdx.x;
  if (blockIdx.x >= 2048) {
    // ---- W2 transpose tile (tail; best-measured placement R9) ----
    int t = blockIdx.x - 2048;               // 0..16383
    int z = t >> 11, rem = t & 2047;         // R=F=2048 (64 r-tiles), C=D=1024 (32)
    int r0 = (rem & 63) * 32, c0 = (rem >> 6) * 32;
    float(*tile)[33] = (float(*)[33])As;     // reuse 16KB LDS
    const float* s = W2 + (size_t)z * F_ * D_;
    u16* dd = W2g + (size_t)z * D_ * F_;
    int xx = tid & 31, yy = tid >> 5;
#pragma unroll
    for (int q = 0; q < 4; ++q)
      tile[yy + q * 8][xx] = s[(size_t)(r0 + yy + q * 8) * D_ + c0 + xx];
    __syncthreads();
    float sc = gamma[(size_t)z * F_ + r0 + xx];
#pragma unroll
    for (int q = 0; q < 4; ++q)
      dd[(size_t)(c0 + yy + q * 8) * F_ + r0 + xx] = f2bf(sc * tile[xx][yy + q * 8]);
    __syncthreads();
    if (tid < 32) {
      float smb = 0.f, smg = 0.f;
      const float* br = beta + (size_t)z * F_ + r0;
      const float* gr = gamma + (size_t)z * F_ + r0;
#pragma unroll
      for (int f = 0; f < 32; ++f) {
        smb += br[f] * tile[f][tid];
        smg += gr[f] * tile[f][tid];
      }
      unsafeAtomicAdd(&Bd[(size_t)z * D_ + c0 + tid], smb);
      unsafeAtomicAdd(&G[(size_t)z * D_ + c0 + tid], smg);
    }
    return;
  }
  int p = blockIdx.x;
  int e = p & 7, slot = p >> 3;
  int tm = slot & 3, bb = (slot >> 2) & 3, tn = slot >> 4;
  int be = bb * 8 + e;
  int t0 = tm * 128, n0 = tn * 128;
  int lane = tid & 63, wid = tid >> 6;
  int wm = wid >> 1, wn = wid & 1;
  int cidx = lane & 15, kq = lane >> 4;

  int srow = tid >> 3;
  int kc = (tid & 7) ^ (srow & 7);
  const u16* pa[4];
  const u16* pb[4];
  const u16* bsrc = W1t + (size_t)e * F_ * D_;
#pragma unroll
  for (int q = 0; q < 4; ++q) {
    int tok = idx[be * TK_ + t0 + q * 32 + srow];
    pa[q] = xb + ((size_t)bb * S_ + tok) * D_ + kc * 8;
    pb[q] = bsrc + (size_t)(n0 + q * 32 + srow) * D_ + kc * 8;
  }
  int aoff[4], boff[4];
#pragma unroll
  for (int f = 0; f < 4; ++f) {
    aoff[f] = (wm * 64 + f * 16 + cidx) * 64;
    boff[f] = (wn * 64 + f * 16 + cidx) * 64;
  }
  int sk0 = (kq ^ (cidx & 7)) * 8;
  int sk1 = ((4 + kq) ^ (cidx & 7)) * 8;

  f32x4 acc[4][4];
#pragma unroll
  for (int f = 0; f < 4; ++f)
#pragma unroll
    for (int g = 0; g < 4; ++g) acc[f][g] = (f32x4){0.f, 0.f, 0.f, 0.f};

  kloop97(pa, pb, As, Bs, acc, D_ / 64, wid, aoff, boff, sk0, sk1);

  float bias[4];
#pragma unroll
  for (int g = 0; g < 4; ++g) bias[g] = b1[e * F_ + n0 + wn * 64 + g * 16 + cidx];
  size_t hbase = (size_t)be * TK_ * F_;
#pragma unroll
  for (int f = 0; f < 4; ++f) {
#pragma unroll
    for (int r = 0; r < 4; ++r) {
      int lr = wm * 64 + f * 16 + kq * 4 + r;
      size_t hb = hbase + (size_t)(t0 + lr) * F_ + n0 + wn * 64 + cidx;
      float vs = 0.f, vss = 0.f;
#pragma unroll
      for (int g = 0; g < 4; ++g) {
        float v = acc[f][g][r] + bias[g];
        float gl = gelu_t(v);
        hbuf[hb + g * 16] = f2bf(gl);
        vs += gl;
        vss += gl * gl;
      }
#pragma unroll
      for (int off = 1; off < 16; off <<= 1) {
        vs += __shfl_xor(vs, off);
        vss += __shfl_xor(vss, off);
      }
      if (cidx == 0) {
        float2 o; o.x = vs; o.y = vss;
        sm[lr][wn] = o;
      }
    }
  }
  __syncthreads();
  if (tid < 128) {
    float2 a = sm[tid][0], b = sm[tid][1];
    float2 o; o.x = a.x + b.x; o.y = a.y + b.y;
    stats2[((size_t)be * TK_ + t0 + tid) * 16 + tn] = o;
  }
}

// ---------------- GEMM2 (R7 form): out = rstd*(h @ W2g) - rstd*mean*G + Bd + b2 ----------------
__global__ __launch_bounds__(256, 2) void gemm2_kernel(const u16* __restrict__ hbuf,
                                                       const u16* __restrict__ W2g,
                                                       const float* __restrict__ b2,
                                                       const int* __restrict__ idx,
                                                       const float* __restrict__ wts,
                                                       float* __restrict__ results,
                                                       const float2* __restrict__ stats2,
                                                       const float* __restrict__ G,
                                                       const float* __restrict__ Bd) {
  int p = blockIdx.x;
  int e = p & 7, slot = p >> 3;
  int tn = slot & 7, tm = (slot >> 3) & 3, bb = slot >> 5;
  int be = bb * 8 + e;
  int t0 = tm * 128, n0 = tn * 128;
  int tid = threadIdx.x, lane = tid & 63, wid = tid >> 6;
  int wm = wid >> 1, wn = wid & 1;
  int cidx = lane & 15, kq = lane >> 4;
  __shared__ u16 As[128 * 64];
  __shared__ u16 Bs[128 * 64];
  __shared__ float smean[128];
  __shared__ float srstd[128];

  if (tid < 128) {
    const float2* sp = stats2 + ((size_t)be * TK_ + t0 + tid) * 16;
    float sum = 0.f, ss = 0.f;
#pragma unroll
    for (int j = 0; j < 16; ++j) {
      float2 v = sp[j];
      sum += v.x;
      ss += v.y;
    }
    float mean = sum * (1.f / F_);
    float var = ss * (1.f / F_) - mean * mean;
    smean[tid] = mean;
    srstd[tid] = rsqrtf(var + 1e-5f);
  }
  __syncthreads();

  int srow = tid >> 3;
  int kc = (tid & 7) ^ (srow & 7);
  const u16* pa[4];
  const u16* pb[4];
  const u16* asrc = hbuf + (size_t)be * TK_ * F_;
  const u16* bsrc = W2g + (size_t)e * D_ * F_;
#pragma unroll
  for (int q = 0; q < 4; ++q) {
    pa[q] = asrc + (size_t)(t0 + q * 32 + srow) * F_ + kc * 8;
    pb[q] = bsrc + (size_t)(n0 + q * 32 + srow) * F_ + kc * 8;
  }
  int aoff[4], boff[4];
#pragma unroll
  for (int f = 0; f < 4; ++f) {
    aoff[f] = (wm * 64 + f * 16 + cidx) * 64;
    boff[f] = (wn * 64 + f * 16 + cidx) * 64;
  }
  int sk0 = (kq ^ (cidx & 7)) * 8;
  int sk1 = ((4 + kq) ^ (cidx & 7)) * 8;

  f32x4 acc[4][4];
#pragma unroll
  for (int f = 0; f < 4; ++f)
#pragma unroll
    for (int g = 0; g < 4; ++g) acc[f][g] = (f32x4){0.f, 0.f, 0.f, 0.f};

  kloop97(pa, pb, As, Bs, acc, F_ / 64, wid, aoff, boff, sk0, sk1);

  int cb = n0 + wn * 64 + cidx;
  float b2v[4], Gv[4], Bdv[4];
#pragma unroll
  for (int g = 0; g < 4; ++g) {
    b2v[g] = b2[e * D_ + cb + g * 16];
    Gv[g] = G[e * D_ + cb + g * 16];
    Bdv[g] = Bd[e * D_ + cb + g * 16];
  }
#pragma unroll
  for (int f = 0; f < 4; ++f) {
#pragma unroll
    for (int r = 0; r < 4; ++r) {
      int lr = wm * 64 + f * 16 + kq * 4 + r;
      int trow = t0 + lr;
      int tok = idx[be * TK_ + trow];
      float wv = wts[be * TK_ + trow];
      float mean = smean[lr], rstd = srstd[lr];
      float* rrow = results + ((size_t)bb * S_ + tok) * D_ + cb;
#pragma unroll
      for (int g = 0; g < 4; ++g) {
        float out = rstd * acc[f][g][r] - rstd * mean * Gv[g] + Bdv[g] + b2v[g];
        unsafeAtomicAdd(rrow + g * 16, wv * out);
      }
    }
  }
}

extern "C" void kernel_launch(void* const* d_in, const int* in_sizes, int n_in,
                              void* d_out, int out_size, void* d_ws, size_t ws_size,
                              hipStream_t stream) {
  const float* x = (const float*)d_in[0];
  const float* Wr = (const float*)d_in[1];
  const float* W1 = (const float*)d_in[2];
  const float* b1 = (const float*)d_in[3];
  const float* gamma = (const float*)d_in[4];
  const float* beta = (const float*)d_in[5];
  const float* W2 = (const float*)d_in[6];
  const float* b2 = (const float*)d_in[7];

  float* results = (float*)d_out;
  float* logits = results + (size_t)B_ * S_ * D_;

  char* ws = (char*)d_ws;
  const size_t OFF_IDX = 0;                                       // 64 KB
  const size_t OFF_WTS = OFF_IDX + (size_t)B_ * E_ * TK_ * 4;     // 64 KB
  const size_t OFF_ST = OFF_WTS + (size_t)B_ * E_ * TK_ * 4;      // 2 MB stats2
  const size_t OFF_G = OFF_ST + (size_t)B_ * E_ * TK_ * 16 * 8;   // 32 KB
  const size_t OFF_BD = OFF_G + (size_t)E_ * D_ * 4;              // 32 KB (contig w/ G)
  const size_t OFF_P = OFF_BD + (size_t)E_ * D_ * 4;              // 512 KB probs
  const size_t OFF_R0 = OFF_P + (size_t)B_ * S_ * E_ * 4;         // 32 MB: xb (W2g alias in small-ws)
  const size_t OFF_R1 = OFF_R0 + (size_t)E_ * D_ * F_ * 2;        // 32 MB: W1t
  const size_t OFF_H = OFF_R1 + (size_t)E_ * D_ * F_ * 2;         // 64 MB: hbuf
  const size_t NEED = OFF_H + (size_t)B_ * E_ * TK_ * F_ * 2;
  const size_t OFF_W2G = NEED;                                    // +32 MB (big-ws only)
  const size_t NEED_BIG = OFF_W2G + (size_t)E_ * D_ * F_ * 2;
  if (ws_size < NEED) return;
  bool bigws = ws_size >= NEED_BIG;

  int* idx = (int*)(ws + OFF_IDX);
  float* wts = (float*)(ws + OFF_WTS);
  float2* stats2 = (float2*)(ws + OFF_ST);
  float* G = (float*)(ws + OFF_G);
  float* Bd = (float*)(ws + OFF_BD);
  float* probs = (float*)(ws + OFF_P);
  u16* xb = (u16*)(ws + OFF_R0);
  u16* W1t = (u16*)(ws + OFF_R1);
  u16* hbuf = (u16*)(ws + OFF_H);
  u16* W2g = bigws ? (u16*)(ws + OFF_W2G) : (u16*)(ws + OFF_R0);

  rc_kernel<<<dim3(B_ * S_ / 4), 256, 0, stream>>>(x, Wr, logits, probs, xb, G);
  tk_tr_kernel<<<dim3(32 + 16384), 1024, 0, stream>>>(probs, idx, wts, W1, W1t, results);
  if (bigws) {
    // gemm1 + W2-transpose tail (W2g non-aliased); best-measured composition (R9)
    gemm1_kernel<<<dim3(2048 + 16384), 256, 0, stream>>>(xb, W1t, b1, idx, hbuf, stats2,
                                                         W2, gamma, beta, W2g, Bd, G);
  } else {
    gemm1_kernel<<<dim3(2048), 256, 0, stream>>>(xb, W1t, b1, idx, hbuf, stats2,
                                                 W2, gamma, beta, W2g, Bd, G);
    // W2g overwrites xb region only after gemm1 completed (in-order stream)
    transpose_cvt_kernel<<<dim3(F_ / 32, D_ / 32, E_), 256, 0, stream>>>(
        W2, W2g, F_, D_, gamma, beta, Bd, G);
  }
  gemm2_kernel<<<dim3(1024), 256, 0, stream>>>(hbuf, W2g, b2, idx, wts, results,
                                               stats2, G, Bd);
}